// Round 10
// baseline (384.005 us; speedup 1.0000x reference)
//
#include <hip/hip_runtime.h>
#include <math.h>

// ---------------------------------------------------------------------------
// HGT layer slice. R21: attend v3 — online softmax + LDS-resident U + tree
// dot. R20 post-mortem: kq fixed (out of top-5); attend leads at 58us, HBM
// 3.0 TB/s (48% achievable), VALU 54% — latency/overhead-bound above the
// ~30-35us gather floor. Fixes: (1) phase-2 loop eliminated via online
// per-rel (max,sum) with exp-rescale; alpha computed in phase 3 from parked
// s (sum rounding differs ~1e-7; softmax continuous; 3x absmax headroom);
// (2) dst's 8 U rows staged to wave-private LDS (2KB/wave, barrier-free) —
// removes the per-edge UF gather + 64-bit addr math from the chain;
// (3) dot split into 2x4 FMA chains (serial 8->5).
//
// kq v5 (R20): k/q block split, R18 double-buffer. nr_gemm v6 (R16):
// register-resident B, streamed A, 2 launches, XCD co-location. Parallel
// scan (R10), [rel][node] layout (R12), qF=VMF[7] alias (R14).
// ---------------------------------------------------------------------------

#define N_NODES 50000
#define N_EDGES 500000
#define DIM 128
#define TT 8
#define RR 8
#define RSQRT_DK 0.08838834764831845f

#define CHUNK_GRID 399               // 399*128 = 51072 >= 50000 + 8*127
#define NODE_LIST_LEN (CHUNK_GRID * 128)
#define GRID_E ((N_EDGES + 255) / 256)   // 1954, also covers N
#define SCAN_BLOCKS ((N_NODES + 255) / 256)   // 196

// nr_gemm v6 geometry: 112 chunks x 448 rows (7 iters x 64) = 50176 >= 50000
// 112 % 8 == 0 -> blocks rel*112+c land on xcd = c%8 for every rel.
#define NR3_CHUNKS 112
#define NR3_ROWS 448
#define NR3_ITERS 7

// word offsets (4B units); _Float16 index = 2*word
#define OFF_U 0                    // UF16 [rel][n][128]
#define OFF_HF 0                   // alias: hF16 [n][128] (dead before U write)
#define OFF_VM 25600000            // VMF16 [rel][n][128]
#define OFF_QF 48000000            // alias: qF16 = VMF[rel=7] slice.
                                   // SAFE: U launch (reads qF) completes
                                   // before VM launch (writes VMF) starts —
                                   // separate kernels, stream-ordered.
#define OFF_KF 51200000
#define OFF_AGGF 54400000
#define OFF_VF 54400000            // alias: vF16 (dead before attend writes agg)
#define OFF_ATTF 57600000          // 65,536 words each, 100k spacing
#define OFF_MSGT 57700000
#define OFF_WVT 57800000
#define OFF_WAT 57900000
#define OFF_INT 58000000           // int region, +701,872 -> 58,701,872 words
#define IO_NLIST 0                 // 51,072
#define IO_CNT_N 51072
#define IO_CUR_N 51080
#define IO_POFF_N 51088
#define IO_DCNT 51104              // 50,000
#define IO_DCUR 101104             // 50,000
#define IO_DOFF 151104             // 50,000
#define IO_DPR 201104              // 500,000 packed (src*8|rel) per CSR slot
#define IO_BLKSUM 701104           // 256 per-scan-block totals
#define IO_BLKOFF 701360           // 256 scanned block offsets; end 701,616

typedef _Float16 half8 __attribute__((ext_vector_type(8)));
typedef _Float16 half4 __attribute__((ext_vector_type(4)));
typedef float f32x4 __attribute__((ext_vector_type(4)));

__global__ void init_kernel(int* wsi) {
    int i = blockIdx.x * blockDim.x + threadIdx.x;
    if (i < NODE_LIST_LEN) wsi[IO_NLIST + i] = -1;
    if (i < 32) wsi[IO_CNT_N + i] = 0;
    if (i < 100000) wsi[IO_DCNT + i] = 0;  // dcnt + dcur contiguous
}

// attF straight [r][d][f]; msgT/WvT/WaT transposed to [.][f][d], all f16
__global__ void convert_kernel(const float* __restrict__ att,
                               const float* __restrict__ msg,
                               const float* __restrict__ Wv,
                               const float* __restrict__ Wa,
                               _Float16* __restrict__ attF,
                               _Float16* __restrict__ msgT,
                               _Float16* __restrict__ WvT,
                               _Float16* __restrict__ WaT) {
    int i = blockIdx.x * 256 + threadIdx.x;
    if (i >= RR * DIM * DIM) return;
    int td = i >> 14, d = (i >> 7) & 127, f = i & 127;
    int tr = (td << 14) + (f << 7) + d;
    attF[i] = (_Float16)att[i];
    msgT[tr] = (_Float16)msg[i];
    WvT[tr] = (_Float16)Wv[i];
    WaT[tr] = (_Float16)Wa[i];
}

__global__ void hconv_kernel(const float* __restrict__ h,
                             _Float16* __restrict__ hF) {
    int i = blockIdx.x * 256 + threadIdx.x;
    if (i < N_NODES * DIM / 4) {
        float4 v = ((const float4*)h)[i];
        half4 o;
        o[0] = (_Float16)v.x; o[1] = (_Float16)v.y;
        o[2] = (_Float16)v.z; o[3] = (_Float16)v.w;
        *(half4*)(hF + (size_t)i * 4) = o;
    }
}

__global__ void hist_kernel(const int* __restrict__ ntype,
                            const int* __restrict__ adj, int* wsi) {
    __shared__ int cn[TT];
    int tid = threadIdx.x;
    if (tid < TT) cn[tid] = 0;
    __syncthreads();
    int i = blockIdx.x * blockDim.x + tid;
    if (i < N_NODES) atomicAdd(&cn[ntype[i]], 1);
    if (i < N_EDGES) atomicAdd(&wsi[IO_DCNT + adj[N_EDGES + i]], 1);
    __syncthreads();
    if (tid < TT && cn[tid] > 0) atomicAdd(&wsi[IO_CNT_N + tid], cn[tid]);
}

__global__ void offsets_kernel(int* wsi) {
    int off = 0;
    for (int t = 0; t < TT; ++t) {
        wsi[IO_POFF_N + t] = off;
        off += ((wsi[IO_CNT_N + t] + 127) >> 7) << 7;  // pad to 128
    }
}

// 3-phase parallel exclusive scan of the 50k dst counts
__global__ __launch_bounds__(256) void scanA_kernel(int* wsi) {
    __shared__ int tmp[256];
    int tid = threadIdx.x;
    int i = blockIdx.x * 256 + tid;
    int v = (i < N_NODES) ? wsi[IO_DCNT + i] : 0;
    tmp[tid] = v;
    __syncthreads();
    for (int off = 1; off < 256; off <<= 1) {
        int t = (tid >= off) ? tmp[tid - off] : 0;
        __syncthreads();
        tmp[tid] += t;
        __syncthreads();
    }
    if (i < N_NODES) wsi[IO_DOFF + i] = tmp[tid] - v;  // block-local exclusive
    if (tid == 255) wsi[IO_BLKSUM + blockIdx.x] = tmp[255];
}

__global__ __launch_bounds__(256) void scanB_kernel(int* wsi) {
    __shared__ int tmp[256];
    int tid = threadIdx.x;
    int v = (tid < SCAN_BLOCKS) ? wsi[IO_BLKSUM + tid] : 0;
    tmp[tid] = v;
    __syncthreads();
    for (int off = 1; off < 256; off <<= 1) {
        int t = (tid >= off) ? tmp[tid - off] : 0;
        __syncthreads();
        tmp[tid] += t;
        __syncthreads();
    }
    wsi[IO_BLKOFF + tid] = tmp[tid] - v;
}

__global__ __launch_bounds__(256) void scanC_kernel(int* wsi) {
    int i = blockIdx.x * 256 + threadIdx.x;
    if (i < N_NODES) wsi[IO_DOFF + i] += wsi[IO_BLKOFF + blockIdx.x];
}

__global__ void scatter_kernel(const int* __restrict__ ntype,
                               const int* __restrict__ etype,
                               const int* __restrict__ adj, int* wsi) {
    __shared__ int cn[TT], bn[TT];
    int tid = threadIdx.x;
    if (tid < TT) cn[tid] = 0;
    __syncthreads();
    int i = blockIdx.x * blockDim.x + tid;
    int t = -1, rnk = 0;
    if (i < N_NODES) {
        t = ntype[i];
        rnk = atomicAdd(&cn[t], 1);
    }
    __syncthreads();
    if (tid < TT && cn[tid] > 0) bn[tid] = atomicAdd(&wsi[IO_CUR_N + tid], cn[tid]);
    __syncthreads();
    if (t >= 0)
        wsi[IO_NLIST + wsi[IO_POFF_N + t] + bn[t] + rnk] = i;
    if (i < N_EDGES) {
        int d = adj[N_EDGES + i];
        int pos = wsi[IO_DOFF + d] + atomicAdd(&wsi[IO_DCUR + d], 1);
        wsi[IO_DPR + pos] = (adj[i] << 3) | etype[i];  // packed src*8|rel
    }
}

// k,q: fp32 vector tile GEMM (score path is argmax-sensitive; R6 post-mortem)
// R20 v5: blockIdx.y selects w (k or q) -> 2x blocks for TLP; inner loop is
// R18's proven single-deep double-buffer. Bit-exact vs R16-R19.
__global__ __launch_bounds__(256, 4) void kq_f32_kernel(
    const float* __restrict__ h, const int* __restrict__ ntype,
    const float* __restrict__ Wk, const float* __restrict__ Wq,
    const int* __restrict__ nlist, _Float16* __restrict__ kout,
    _Float16* __restrict__ qout) {
    __shared__ float hl[64][DIM + 4];
    __shared__ int nid[64];
    int tid = threadIdx.x;
    int base = blockIdx.x * 64;
    if (tid < 64) nid[tid] = nlist[base + tid];
    __syncthreads();
    if (nid[0] < 0) return;
    int t = ntype[nid[0]];

    for (int r2 = 0; r2 < 64; r2 += 2) {
        int row = r2 + (tid >> 7);
        int col = tid & 127;
        int n = nid[row];
        if (n < 0) n = 0;
        hl[row][col] = h[(size_t)n * DIM + col];
    }
    __syncthreads();
    int te = tid >> 5, tc = tid & 31;   // te-group owns 8 nodes

    int w = blockIdx.y;
    const float* W = (w == 0 ? Wk : Wq) + (size_t)t * DIM * DIM;
    const float4* W4 = (const float4*)W;
    _Float16* O = (w == 0 ? kout : qout);
    float acc[8][4] = {};
    // prefetch i=0 batch
    float4 cur0 = W4[0 * 32 + tc];
    float4 cur1 = W4[1 * 32 + tc];
    float4 cur2 = W4[2 * 32 + tc];
    float4 cur3 = W4[3 * 32 + tc];
    for (int i = 0; i < DIM; i += 4) {
        // issue next batch BEFORE consuming cur (double-buffer; safe
        // wrap-to-0 index on last iter keeps loads in-bounds, unused)
        int ip = (i + 4 < DIM) ? (i + 4) : 0;
        float4 nxt0 = W4[(ip + 0) * 32 + tc];
        float4 nxt1 = W4[(ip + 1) * 32 + tc];
        float4 nxt2 = W4[(ip + 2) * 32 + tc];
        float4 nxt3 = W4[(ip + 3) * 32 + tc];
#pragma unroll
        for (int j = 0; j < 8; ++j) {
            // hl row 528B (16B-aligned), address uniform per te-group
            // -> broadcast ds_read_b128, conflict-free
            float4 hv = *(const float4*)&hl[te * 8 + j][i];
            acc[j][0] += hv.x * cur0.x;
            acc[j][1] += hv.x * cur0.y;
            acc[j][2] += hv.x * cur0.z;
            acc[j][3] += hv.x * cur0.w;
            acc[j][0] += hv.y * cur1.x;
            acc[j][1] += hv.y * cur1.y;
            acc[j][2] += hv.y * cur1.z;
            acc[j][3] += hv.y * cur1.w;
            acc[j][0] += hv.z * cur2.x;
            acc[j][1] += hv.z * cur2.y;
            acc[j][2] += hv.z * cur2.z;
            acc[j][3] += hv.z * cur2.w;
            acc[j][0] += hv.w * cur3.x;
            acc[j][1] += hv.w * cur3.y;
            acc[j][2] += hv.w * cur3.z;
            acc[j][3] += hv.w * cur3.w;
        }
        cur0 = nxt0;
        cur1 = nxt1;
        cur2 = nxt2;
        cur3 = nxt3;
    }
#pragma unroll
    for (int j = 0; j < 8; ++j) {
        int n = nid[te * 8 + j];
        if (n >= 0) {
            half4 o;
            o[0] = (_Float16)acc[j][0];
            o[1] = (_Float16)acc[j][1];
            o[2] = (_Float16)acc[j][2];
            o[3] = (_Float16)acc[j][3];
            *(half4*)(O + (size_t)n * DIM + tc * 4) = o;
        }
    }
}

// v: 128-node type-uniform chunk MFMA GEMM (value path: f16-tolerant)
__global__ __launch_bounds__(256) void vproj_kernel(
    const _Float16* __restrict__ hF, const int* __restrict__ ntype,
    const _Float16* __restrict__ WvT, const int* __restrict__ nlist,
    _Float16* __restrict__ vout) {
    __shared__ int nid[128];
    int tid = threadIdx.x;
    if (tid < 128) nid[tid] = nlist[blockIdx.x * 128 + tid];
    __syncthreads();
    if (nid[0] < 0) return;
    int t = ntype[nid[0]];
    int wv = tid >> 6, lane = tid & 63, l16 = lane & 15, quad = lane >> 4;
    int r0 = wv * 32;
    int nA[2];
#pragma unroll
    for (int m = 0; m < 2; ++m) nA[m] = nid[r0 + m * 16 + l16];
    const _Float16* B = WvT + (t << 14);
    f32x4 acc[2][8];
#pragma unroll
    for (int m = 0; m < 2; ++m)
#pragma unroll
        for (int c = 0; c < 8; ++c) acc[m][c] = (f32x4){0.f, 0.f, 0.f, 0.f};
    for (int kk = 0; kk < 4; ++kk) {
        int kb = kk * 32 + quad * 8;
        half8 a[2];
#pragma unroll
        for (int m = 0; m < 2; ++m)
            a[m] = (nA[m] >= 0)
                       ? *(const half8*)(hF + (size_t)nA[m] * DIM + kb)
                       : (half8){0, 0, 0, 0, 0, 0, 0, 0};
#pragma unroll
        for (int c = 0; c < 8; ++c) {
            half8 b = *(const half8*)(B + (c * 16 + l16) * DIM + kb);
#pragma unroll
            for (int m = 0; m < 2; ++m)
                acc[m][c] = __builtin_amdgcn_mfma_f32_16x16x32_f16(
                    a[m], b, acc[m][c], 0, 0, 0);
        }
    }
#pragma unroll
    for (int m = 0; m < 2; ++m)
#pragma unroll
        for (int c = 0; c < 8; ++c)
#pragma unroll
            for (int rg = 0; rg < 4; ++rg) {
                int node = nid[r0 + m * 16 + quad * 4 + rg];
                if (node >= 0)
                    vout[(size_t)node * DIM + c * 16 + l16] =
                        (_Float16)acc[m][c][rg];
            }
}

// ---------------------------------------------------------------------------
// nr_gemm v6 (R16-proven): one block = one rel; B register-resident; stream
// NR3_ITERS x 64-row tiles with double-buffered A prefetch.
// ---------------------------------------------------------------------------
__global__ __launch_bounds__(256, 2) void nr_gemm3_kernel(
    const _Float16* __restrict__ A, const _Float16* __restrict__ B8,
    _Float16* __restrict__ Out, const float* __restrict__ pri, int isU) {
    __shared__ _Float16 stage[4][16][136];
    int bid = blockIdx.x;
    int rel = bid / NR3_CHUNKS;
    int chunk = bid - rel * NR3_CHUNKS;
    float scale = isU ? pri[rel] * RSQRT_DK : 1.0f;
    const _Float16* Bb = B8 + (rel << 14);
    int tid = threadIdx.x;
    int wv = tid >> 6, lane = tid & 63;
    int l16 = lane & 15, quad = lane >> 4;

    // B fragments once: bfrag[c][kk] covers B-row c*16+l16, k=kk*32+quad*8
    half8 bfrag[8][4];
#pragma unroll
    for (int c = 0; c < 8; ++c)
#pragma unroll
        for (int kk = 0; kk < 4; ++kk)
            bfrag[c][kk] =
                *(const half8*)(Bb + (c * 16 + l16) * DIM + kk * 32 + quad * 8);

    _Float16* Orel = Out + (size_t)rel * N_NODES * DIM;
    int base = chunk * NR3_ROWS + wv * 16;  // this wave's first tile row

    // prefetch tile 0
    half8 aNow[4], aNext[4];
    {
        int nodeA = base + l16;
#pragma unroll
        for (int kk = 0; kk < 4; ++kk)
            aNow[kk] = (nodeA < N_NODES)
                           ? *(const half8*)(A + (size_t)nodeA * DIM +
                                             kk * 32 + quad * 8)
                           : (half8){0, 0, 0, 0, 0, 0, 0, 0};
    }

    for (int it = 0; it < NR3_ITERS; ++it) {
        int row0 = base + it * 64;
        // prefetch next tile's A while this tile computes
        if (it + 1 < NR3_ITERS) {
            int nodeA = row0 + 64 + l16;
#pragma unroll
            for (int kk = 0; kk < 4; ++kk)
                aNext[kk] = (nodeA < N_NODES)
                                ? *(const half8*)(A + (size_t)nodeA * DIM +
                                                  kk * 32 + quad * 8)
                                : (half8){0, 0, 0, 0, 0, 0, 0, 0};
        }
        f32x4 acc[8];
#pragma unroll
        for (int c = 0; c < 8; ++c) acc[c] = (f32x4){0.f, 0.f, 0.f, 0.f};
#pragma unroll
        for (int kk = 0; kk < 4; ++kk)
#pragma unroll
            for (int c = 0; c < 8; ++c)
                acc[c] = __builtin_amdgcn_mfma_f32_16x16x32_f16(
                    bfrag[c][kk], aNow[kk], acc[c], 0, 0, 0);
        // stage transposed acc into wave-private LDS: row = local node l16,
        // feature = c*16 + quad*4 + rg
#pragma unroll
        for (int c = 0; c < 8; ++c) {
            half4 o;
#pragma unroll
            for (int rg = 0; rg < 4; ++rg)
                o[rg] = (_Float16)(acc[c][rg] * scale);
            *(half4*)&stage[wv][l16][c * 16 + quad * 4] = o;
        }
        // read back row-wise: 4 x (4 rows x 256B) = 1KiB contiguous stores
        _Float16* Op = Orel + (size_t)row0 * DIM;
#pragma unroll
        for (int s = 0; s < 4; ++s) {
            int row = s * 4 + quad;
            if (row0 + row < N_NODES) {
                half8 v = *(const half8*)&stage[wv][row][l16 * 8];
                *(half8*)(Op + (size_t)row * DIM + l16 * 8) = v;
            }
        }
#pragma unroll
        for (int kk = 0; kk < 4; ++kk) aNow[kk] = aNext[kk];
    }
}

// ---------------------------------------------------------------------------
// attend v3 (R21): online per-rel softmax (phase-2 loop removed), U rows
// LDS-resident per wave (barrier-free), tree dot. Parked value is s (score);
// alpha computed in the accumulate loop as exp(s - m_final[rel]) * inv[rel].
// ---------------------------------------------------------------------------
__global__ __launch_bounds__(256) void attend_kernel(
    const _Float16* __restrict__ kF, const _Float16* __restrict__ UF,
    const _Float16* __restrict__ VMF, const int* __restrict__ dpr,
    const int* __restrict__ doff, const int* __restrict__ dcnt,
    _Float16* __restrict__ aggF) {
    __shared__ _Float16 uls[4][8][136];  // per-wave: this dst's 8 U rows
    int wv = threadIdx.x >> 6, lane = threadIdx.x & 63;
    int dst = blockIdx.x * 4 + wv;
    if (dst >= N_NODES) return;
    int l16 = lane & 15, g = lane >> 4, l8 = lane & 7;
    int beg = doff[dst], cnt = dcnt[dst];

    // stage U[0..7][dst][:] into wave-private LDS (same wave writes then
    // reads -> vmcnt/lgkmcnt ordering suffices, no barrier)
    {
        int rr = lane >> 3;           // U row (rel) 0..7
        int c0 = (lane & 7) * 16;     // 16 halves = 32B per lane
        const _Float16* Ur = UF + ((size_t)rr * N_NODES + dst) * DIM + c0;
        *(half8*)&uls[wv][rr][c0] = *(const half8*)Ur;
        *(half8*)&uls[wv][rr][c0 + 8] = *(const half8*)(Ur + 8);
    }

    float m_own = -3e38f, sum_own = 0.f;
    float s0 = 0.f, s1 = 0.f, s2 = 0.f;
    int p0 = 0, p1 = 0, p2 = 0;

    // phase 1: scores; park (s, pr); ONLINE per-rel (max, sum) on owning lane
    for (int j0 = 0; j0 < cnt; j0 += 4) {
        int j = j0 + g;
        bool valid = j < cnt;
        int pr = valid ? dpr[beg + j] : 0;
        int src = pr >> 3, rel = pr & 7;
        half8 kv = *(const half8*)(kF + (size_t)src * DIM + l16 * 8);
        half8 uv = *(const half8*)&uls[wv][rel][l16 * 8];
        float sa = 0.f, sb = 0.f;
#pragma unroll
        for (int i = 0; i < 4; ++i) sa += (float)kv[i] * (float)uv[i];
#pragma unroll
        for (int i = 4; i < 8; ++i) sb += (float)kv[i] * (float)uv[i];
        float s = sa + sb;
        s += __shfl_xor(s, 1, 16);
        s += __shfl_xor(s, 2, 16);
        s += __shfl_xor(s, 4, 16);
        s += __shfl_xor(s, 8, 16);
        if (!valid) s = -3e38f;
        int slot = j0 >> 6;            // wave-uniform
        int idx = (j0 >> 2) & 15;      // wave-uniform
        if (l16 == idx) {
            if (slot == 0) { s0 = s; p0 = pr; }
            else if (slot == 1) { s1 = s; p1 = pr; }
            else if (slot == 2) { s2 = s; p2 = pr; }
        }
        if (valid && l8 == rel) {
            if (s > m_own) {
                sum_own *= __expf(m_own - s);  // 0 * exp(-huge) = 0 first time
                m_own = s;
            }
            sum_own += __expf(s - m_own);
        }
    }
    // joint merge of (m, sum) across the 4 groups (exp-rescale combine)
    {
        float m2 = __shfl_xor(m_own, 16, 64);
        float t2 = __shfl_xor(sum_own, 16, 64);
        float mn = fmaxf(m_own, m2);
        sum_own = sum_own * __expf(m_own - mn) + t2 * __expf(m2 - mn);
        m_own = mn;
        m2 = __shfl_xor(m_own, 32, 64);
        t2 = __shfl_xor(sum_own, 32, 64);
        mn = fmaxf(m_own, m2);
        sum_own = sum_own * __expf(m_own - mn) + t2 * __expf(m2 - mn);
        m_own = mn;
    }
    float inv_own = (sum_own > 0.f) ? 1.f / sum_own : 0.f;

    // phase 2: alpha = exp(s - m[rel]) * inv[rel]; acc += alpha * VM[rel][src]
    float acc[8] = {0.f, 0.f, 0.f, 0.f, 0.f, 0.f, 0.f, 0.f};
    for (int j0 = 0; j0 < cnt; j0 += 4) {
        int j = j0 + g;
        bool valid = j < cnt;
        int slot = j0 >> 6;
        int idx = (j0 >> 2) & 15;
        float s;
        int pr;
        if (slot < 3) {
            float sv = (slot == 0) ? s0 : (slot == 1) ? s1 : s2;
            int pv = (slot == 0) ? p0 : (slot == 1) ? p1 : p2;
            s = __shfl(sv, idx, 16);
            pr = __shfl(pv, idx, 16);
        } else {  // overflow fallback: recompute (cnt>192 ~ never at deg~10)
            pr = valid ? dpr[beg + j] : 0;
            int src = pr >> 3, rel = pr & 7;
            half8 kv = *(const half8*)(kF + (size_t)src * DIM + l16 * 8);
            half8 uv = *(const half8*)&uls[wv][rel][l16 * 8];
            float sa = 0.f, sb = 0.f;
#pragma unroll
            for (int i = 0; i < 4; ++i) sa += (float)kv[i] * (float)uv[i];
#pragma unroll
            for (int i = 4; i < 8; ++i) sb += (float)kv[i] * (float)uv[i];
            s = sa + sb;
            s += __shfl_xor(s, 1, 16);
            s += __shfl_xor(s, 2, 16);
            s += __shfl_xor(s, 4, 16);
            s += __shfl_xor(s, 8, 16);
        }
        int rel = pr & 7, src = pr >> 3;
        float mr = __shfl(m_own, rel, 8);
        float iv = __shfl(inv_own, rel, 8);
        float alpha = valid ? __expf(s - mr) * iv : 0.f;
        half8 v = *(const half8*)(VMF + ((size_t)rel * N_NODES + src) * DIM +
                                  l16 * 8);
#pragma unroll
        for (int i = 0; i < 8; ++i) acc[i] += alpha * (float)v[i];
    }
    // merge acc across the 4 groups (each covers the full 128 dims)
#pragma unroll
    for (int i = 0; i < 8; ++i) {
        acc[i] += __shfl_xor(acc[i], 16, 64);
        acc[i] += __shfl_xor(acc[i], 32, 64);
    }
    if (g == 0) {
        half8 o;
#pragma unroll
        for (int i = 0; i < 8; ++i) o[i] = (_Float16)acc[i];
        *(half8*)(aggF + (size_t)dst * DIM + l16 * 8) = o;
    }
}

// out: 128-node type-uniform chunk MFMA GEMM, fp32 stores with sigmoid gate
__global__ __launch_bounds__(256) void out_kernel(
    const _Float16* __restrict__ aggF, const int* __restrict__ ntype,
    const _Float16* __restrict__ WaT, const float* __restrict__ skip,
    const int* __restrict__ nlist, float* __restrict__ out) {
    __shared__ int nid[128];
    int tid = threadIdx.x;
    if (tid < 128) nid[tid] = nlist[blockIdx.x * 128 + tid];
    __syncthreads();
    if (nid[0] < 0) return;
    int t = ntype[nid[0]];
    float sig = 1.f / (1.f + __expf(-skip[t]));
    int wv = tid >> 6, lane = tid & 63, l16 = lane & 15, quad = lane >> 4;
    int r0 = wv * 32;
    int nA[2];
#pragma unroll
    for (int m = 0; m < 2; ++m) nA[m] = nid[r0 + m * 16 + l16];
    const _Float16* B = WaT + (t << 14);
    f32x4 acc[2][8];
#pragma unroll
    for (int m = 0; m < 2; ++m)
#pragma unroll
        for (int c = 0; c < 8; ++c) acc[m][c] = (f32x4){0.f, 0.f, 0.f, 0.f};
    for (int kk = 0; kk < 4; ++kk) {
        int kb = kk * 32 + quad * 8;
        half8 a[2];
#pragma unroll
        for (int m = 0; m < 2; ++m)
            a[m] = (nA[m] >= 0)
                       ? *(const half8*)(aggF + (size_t)nA[m] * DIM + kb)
                       : (half8){0, 0, 0, 0, 0, 0, 0, 0};
#pragma unroll
        for (int c = 0; c < 8; ++c) {
            half8 b = *(const half8*)(B + (c * 16 + l16) * DIM + kb);
#pragma unroll
            for (int m = 0; m < 2; ++m)
                acc[m][c] = __builtin_amdgcn_mfma_f32_16x16x32_f16(
                    a[m], b, acc[m][c], 0, 0, 0);
        }
    }
#pragma unroll
    for (int m = 0; m < 2; ++m)
#pragma unroll
        for (int c = 0; c < 8; ++c)
#pragma unroll
            for (int rg = 0; rg < 4; ++rg) {
                int node = nid[r0 + m * 16 + quad * 4 + rg];
                if (node >= 0)
                    out[(size_t)node * DIM + c * 16 + l16] =
                        acc[m][c][rg] * sig;
            }
}

extern "C" void kernel_launch(void* const* d_in, const int* in_sizes, int n_in,
                              void* d_out, int out_size, void* d_ws,
                              size_t ws_size, hipStream_t stream) {
    const float* h = (const float*)d_in[0];
    const int* adj = (const int*)d_in[1];
    const int* etype = (const int*)d_in[2];
    const int* ntype = (const int*)d_in[3];
    const float* Wk = (const float*)d_in[6];
    const float* Wq = (const float*)d_in[7];
    const float* Wv = (const float*)d_in[8];
    const float* Wa = (const float*)d_in[9];
    const float* pri = (const float*)d_in[10];
    const float* att = (const float*)d_in[11];
    const float* msg = (const float*)d_in[12];
    const float* skip = (const float*)d_in[13];
    float* out = (float*)d_out;

    int* wsi = (int*)d_ws + OFF_INT;
    _Float16* wsh = (_Float16*)d_ws;
    _Float16* UF = wsh + (size_t)OFF_U * 2;
    _Float16* hF = wsh + (size_t)OFF_HF * 2;
    _Float16* VMF = wsh + (size_t)OFF_VM * 2;
    _Float16* qF = wsh + (size_t)OFF_QF * 2;
    _Float16* kF = wsh + (size_t)OFF_KF * 2;
    _Float16* aggF = wsh + (size_t)OFF_AGGF * 2;
    _Float16* vF = wsh + (size_t)OFF_VF * 2;
    _Float16* attF = wsh + (size_t)OFF_ATTF * 2;
    _Float16* msgT = wsh + (size_t)OFF_MSGT * 2;
    _Float16* WvT = wsh + (size_t)OFF_WVT * 2;
    _Float16* WaT = wsh + (size_t)OFF_WAT * 2;

    init_kernel<<<(100000 + 255) / 256, 256, 0, stream>>>(wsi);
    convert_kernel<<<(RR * DIM * DIM + 255) / 256, 256, 0, stream>>>(
        att, msg, Wv, Wa, attF, msgT, WvT, WaT);
    hconv_kernel<<<(N_NODES * DIM / 4 + 255) / 256, 256, 0, stream>>>(h, hF);
    hist_kernel<<<GRID_E, 256, 0, stream>>>(ntype, adj, wsi);
    offsets_kernel<<<1, 1, 0, stream>>>(wsi);
    scanA_kernel<<<SCAN_BLOCKS, 256, 0, stream>>>(wsi);
    scanB_kernel<<<1, 256, 0, stream>>>(wsi);
    scanC_kernel<<<SCAN_BLOCKS, 256, 0, stream>>>(wsi);
    scatter_kernel<<<GRID_E, 256, 0, stream>>>(ntype, etype, adj, wsi);
    {
        dim3 g(CHUNK_GRID * 2, 2);  // x: 64-node chunks, y: w (k=0, q=1)
        kq_f32_kernel<<<g, 256, 0, stream>>>(h, ntype, Wk, Wq,
                                             wsi + IO_NLIST, kF, qF);
    }
    vproj_kernel<<<CHUNK_GRID, 256, 0, stream>>>(hF, ntype, WvT,
                                                 wsi + IO_NLIST, vF);
    // U pass (reads qF) fully precedes VM pass (writes VMF; qF aliases
    // VMF[7]) — stream ordering guarantees no overlap.
    nr_gemm3_kernel<<<RR * NR3_CHUNKS, 256, 0, stream>>>(qF, attF, UF, pri, 1);
    nr_gemm3_kernel<<<RR * NR3_CHUNKS, 256, 0, stream>>>(vF, msgT, VMF, pri, 0);
    attend_kernel<<<(N_NODES + 3) / 4, 256, 0, stream>>>(
        kF, UF, VMF, wsi + IO_DPR, wsi + IO_DOFF, wsi + IO_DCNT, aggF);
    out_kernel<<<CHUNK_GRID, 256, 0, stream>>>(aggF, ntype, WaT, skip,
                                               wsi + IO_NLIST, out);
}

// Round 11
// 375.625 us; speedup vs baseline: 1.0223x; 1.0223x over previous
//
#include <hip/hip_runtime.h>
#include <math.h>

// ---------------------------------------------------------------------------
// HGT layer slice. R22: attend v4 — flipped score factorization, U deleted.
// R21 post-mortem: online softmax was neutral — U staging streams all 8
// rels/dst (102MB, the dominant term of attend's 171MB FETCH) + 1.26M bank-
// conflict cycles offset the removed loop. Fix: score = (k@att)·q instead of
// k·(att@q): nr_gemm pass 1 now computes kA[rel][src] (B = attT, transposed
// like msgT; pri scale moves onto kA — linear, same f16 rounding structure
// as the passing U path). attend gathers kA[rel][src] per edge (ONE gather
// replaces k-gather + U-read; only ~73MB of distinct rows touched) and
// keeps q[dst] in registers. No LDS, no staging, no conflicts.
// Workspace re-plumb (alias-audited): KA@0 (hF dead after vproj), kF@25.6M
// (clobbered only by VM pass after last read), qF@51.2M (nothing writes it
// after kq — the old qF=VMF[7] hazard is gone entirely).
//
// kq v5 (R20), nr_gemm v6 (R16), online softmax (R21), parallel scan (R10),
// [rel][node] layout (R12).
// ---------------------------------------------------------------------------

#define N_NODES 50000
#define N_EDGES 500000
#define DIM 128
#define TT 8
#define RR 8
#define RSQRT_DK 0.08838834764831845f

#define CHUNK_GRID 399               // 399*128 = 51072 >= 50000 + 8*127
#define NODE_LIST_LEN (CHUNK_GRID * 128)
#define GRID_E ((N_EDGES + 255) / 256)   // 1954, also covers N
#define SCAN_BLOCKS ((N_NODES + 255) / 256)   // 196

// nr_gemm v6 geometry: 112 chunks x 448 rows (7 iters x 64) = 50176 >= 50000
// 112 % 8 == 0 -> blocks rel*112+c land on xcd = c%8 for every rel.
#define NR3_CHUNKS 112
#define NR3_ROWS 448
#define NR3_ITERS 7

// word offsets (4B units); _Float16 index = 2*word
// Lifetime audit (stream order: kq -> vproj -> nrg1(KA) -> nrg2(VM) ->
// attend -> out):
//   KA  @ 0..25.6M    written by nrg1; hF alias dead after vproj. read attend
//   VMF @ 25.6..51.2M written by nrg2; kF alias dead after nrg1. read attend
//   kF  @ 25.6M       written by kq, read by nrg1, then clobbered by nrg2 OK
//   qF  @ 51.2M       written by kq, read by attend; nothing else writes it
//   aggF@ 54.4M       written by attend, read by out; vF alias dead by then
#define OFF_KA 0                   // kA f16 [rel][n][128]
#define OFF_HF 0                   // alias: hF16 (dead before KA write)
#define OFF_VM 25600000            // VMF16 [rel][n][128]
#define OFF_KF 25600000            // alias: kF16 (dead before VM write)
#define OFF_QF 51200000            // qF16 — no aliasing writer after kq
#define OFF_AGGF 54400000
#define OFF_VF 54400000            // alias: vF16 (dead before attend writes agg)
#define OFF_ATTT 57600000          // attT [r][f][d] (transposed), 100k spacing
#define OFF_MSGT 57700000
#define OFF_WVT 57800000
#define OFF_WAT 57900000
#define OFF_INT 58000000           // int region, +701,872 -> 58,701,872 words
#define IO_NLIST 0                 // 51,072
#define IO_CNT_N 51072
#define IO_CUR_N 51080
#define IO_POFF_N 51088
#define IO_DCNT 51104              // 50,000
#define IO_DCUR 101104             // 50,000
#define IO_DOFF 151104             // 50,000
#define IO_DPR 201104              // 500,000 packed (src*8|rel) per CSR slot
#define IO_BLKSUM 701104           // 256 per-scan-block totals
#define IO_BLKOFF 701360           // 256 scanned block offsets; end 701,616

typedef _Float16 half8 __attribute__((ext_vector_type(8)));
typedef _Float16 half4 __attribute__((ext_vector_type(4)));
typedef float f32x4 __attribute__((ext_vector_type(4)));

__global__ void init_kernel(int* wsi) {
    int i = blockIdx.x * blockDim.x + threadIdx.x;
    if (i < NODE_LIST_LEN) wsi[IO_NLIST + i] = -1;
    if (i < 32) wsi[IO_CNT_N + i] = 0;
    if (i < 100000) wsi[IO_DCNT + i] = 0;  // dcnt + dcur contiguous
}

// ALL weight tensors transposed to [.][f][d] f16 (attT now transposed too —
// nr_gemm pass 1 computes kA = k @ att, which needs B[f][d])
__global__ void convert_kernel(const float* __restrict__ att,
                               const float* __restrict__ msg,
                               const float* __restrict__ Wv,
                               const float* __restrict__ Wa,
                               _Float16* __restrict__ attT,
                               _Float16* __restrict__ msgT,
                               _Float16* __restrict__ WvT,
                               _Float16* __restrict__ WaT) {
    int i = blockIdx.x * 256 + threadIdx.x;
    if (i >= RR * DIM * DIM) return;
    int td = i >> 14, d = (i >> 7) & 127, f = i & 127;
    int tr = (td << 14) + (f << 7) + d;
    attT[tr] = (_Float16)att[i];
    msgT[tr] = (_Float16)msg[i];
    WvT[tr] = (_Float16)Wv[i];
    WaT[tr] = (_Float16)Wa[i];
}

__global__ void hconv_kernel(const float* __restrict__ h,
                             _Float16* __restrict__ hF) {
    int i = blockIdx.x * 256 + threadIdx.x;
    if (i < N_NODES * DIM / 4) {
        float4 v = ((const float4*)h)[i];
        half4 o;
        o[0] = (_Float16)v.x; o[1] = (_Float16)v.y;
        o[2] = (_Float16)v.z; o[3] = (_Float16)v.w;
        *(half4*)(hF + (size_t)i * 4) = o;
    }
}

__global__ void hist_kernel(const int* __restrict__ ntype,
                            const int* __restrict__ adj, int* wsi) {
    __shared__ int cn[TT];
    int tid = threadIdx.x;
    if (tid < TT) cn[tid] = 0;
    __syncthreads();
    int i = blockIdx.x * blockDim.x + tid;
    if (i < N_NODES) atomicAdd(&cn[ntype[i]], 1);
    if (i < N_EDGES) atomicAdd(&wsi[IO_DCNT + adj[N_EDGES + i]], 1);
    __syncthreads();
    if (tid < TT && cn[tid] > 0) atomicAdd(&wsi[IO_CNT_N + tid], cn[tid]);
}

__global__ void offsets_kernel(int* wsi) {
    int off = 0;
    for (int t = 0; t < TT; ++t) {
        wsi[IO_POFF_N + t] = off;
        off += ((wsi[IO_CNT_N + t] + 127) >> 7) << 7;  // pad to 128
    }
}

// 3-phase parallel exclusive scan of the 50k dst counts
__global__ __launch_bounds__(256) void scanA_kernel(int* wsi) {
    __shared__ int tmp[256];
    int tid = threadIdx.x;
    int i = blockIdx.x * 256 + tid;
    int v = (i < N_NODES) ? wsi[IO_DCNT + i] : 0;
    tmp[tid] = v;
    __syncthreads();
    for (int off = 1; off < 256; off <<= 1) {
        int t = (tid >= off) ? tmp[tid - off] : 0;
        __syncthreads();
        tmp[tid] += t;
        __syncthreads();
    }
    if (i < N_NODES) wsi[IO_DOFF + i] = tmp[tid] - v;  // block-local exclusive
    if (tid == 255) wsi[IO_BLKSUM + blockIdx.x] = tmp[255];
}

__global__ __launch_bounds__(256) void scanB_kernel(int* wsi) {
    __shared__ int tmp[256];
    int tid = threadIdx.x;
    int v = (tid < SCAN_BLOCKS) ? wsi[IO_BLKSUM + tid] : 0;
    tmp[tid] = v;
    __syncthreads();
    for (int off = 1; off < 256; off <<= 1) {
        int t = (tid >= off) ? tmp[tid - off] : 0;
        __syncthreads();
        tmp[tid] += t;
        __syncthreads();
    }
    wsi[IO_BLKOFF + tid] = tmp[tid] - v;
}

__global__ __launch_bounds__(256) void scanC_kernel(int* wsi) {
    int i = blockIdx.x * 256 + threadIdx.x;
    if (i < N_NODES) wsi[IO_DOFF + i] += wsi[IO_BLKOFF + blockIdx.x];
}

__global__ void scatter_kernel(const int* __restrict__ ntype,
                               const int* __restrict__ etype,
                               const int* __restrict__ adj, int* wsi) {
    __shared__ int cn[TT], bn[TT];
    int tid = threadIdx.x;
    if (tid < TT) cn[tid] = 0;
    __syncthreads();
    int i = blockIdx.x * blockDim.x + tid;
    int t = -1, rnk = 0;
    if (i < N_NODES) {
        t = ntype[i];
        rnk = atomicAdd(&cn[t], 1);
    }
    __syncthreads();
    if (tid < TT && cn[tid] > 0) bn[tid] = atomicAdd(&wsi[IO_CUR_N + tid], cn[tid]);
    __syncthreads();
    if (t >= 0)
        wsi[IO_NLIST + wsi[IO_POFF_N + t] + bn[t] + rnk] = i;
    if (i < N_EDGES) {
        int d = adj[N_EDGES + i];
        int pos = wsi[IO_DOFF + d] + atomicAdd(&wsi[IO_DCUR + d], 1);
        wsi[IO_DPR + pos] = (adj[i] << 3) | etype[i];  // packed src*8|rel
    }
}

// k,q: fp32 vector tile GEMM (score path is argmax-sensitive; R6 post-mortem)
// R20 v5: blockIdx.y selects w (k or q) -> 2x blocks for TLP; inner loop is
// R18's proven single-deep double-buffer. Bit-exact vs R16-R21.
__global__ __launch_bounds__(256, 4) void kq_f32_kernel(
    const float* __restrict__ h, const int* __restrict__ ntype,
    const float* __restrict__ Wk, const float* __restrict__ Wq,
    const int* __restrict__ nlist, _Float16* __restrict__ kout,
    _Float16* __restrict__ qout) {
    __shared__ float hl[64][DIM + 4];
    __shared__ int nid[64];
    int tid = threadIdx.x;
    int base = blockIdx.x * 64;
    if (tid < 64) nid[tid] = nlist[base + tid];
    __syncthreads();
    if (nid[0] < 0) return;
    int t = ntype[nid[0]];

    for (int r2 = 0; r2 < 64; r2 += 2) {
        int row = r2 + (tid >> 7);
        int col = tid & 127;
        int n = nid[row];
        if (n < 0) n = 0;
        hl[row][col] = h[(size_t)n * DIM + col];
    }
    __syncthreads();
    int te = tid >> 5, tc = tid & 31;   // te-group owns 8 nodes

    int w = blockIdx.y;
    const float* W = (w == 0 ? Wk : Wq) + (size_t)t * DIM * DIM;
    const float4* W4 = (const float4*)W;
    _Float16* O = (w == 0 ? kout : qout);
    float acc[8][4] = {};
    // prefetch i=0 batch
    float4 cur0 = W4[0 * 32 + tc];
    float4 cur1 = W4[1 * 32 + tc];
    float4 cur2 = W4[2 * 32 + tc];
    float4 cur3 = W4[3 * 32 + tc];
    for (int i = 0; i < DIM; i += 4) {
        // issue next batch BEFORE consuming cur (double-buffer; safe
        // wrap-to-0 index on last iter keeps loads in-bounds, unused)
        int ip = (i + 4 < DIM) ? (i + 4) : 0;
        float4 nxt0 = W4[(ip + 0) * 32 + tc];
        float4 nxt1 = W4[(ip + 1) * 32 + tc];
        float4 nxt2 = W4[(ip + 2) * 32 + tc];
        float4 nxt3 = W4[(ip + 3) * 32 + tc];
#pragma unroll
        for (int j = 0; j < 8; ++j) {
            // hl row 528B (16B-aligned), address uniform per te-group
            // -> broadcast ds_read_b128, conflict-free
            float4 hv = *(const float4*)&hl[te * 8 + j][i];
            acc[j][0] += hv.x * cur0.x;
            acc[j][1] += hv.x * cur0.y;
            acc[j][2] += hv.x * cur0.z;
            acc[j][3] += hv.x * cur0.w;
            acc[j][0] += hv.y * cur1.x;
            acc[j][1] += hv.y * cur1.y;
            acc[j][2] += hv.y * cur1.z;
            acc[j][3] += hv.y * cur1.w;
            acc[j][0] += hv.z * cur2.x;
            acc[j][1] += hv.z * cur2.y;
            acc[j][2] += hv.z * cur2.z;
            acc[j][3] += hv.z * cur2.w;
            acc[j][0] += hv.w * cur3.x;
            acc[j][1] += hv.w * cur3.y;
            acc[j][2] += hv.w * cur3.z;
            acc[j][3] += hv.w * cur3.w;
        }
        cur0 = nxt0;
        cur1 = nxt1;
        cur2 = nxt2;
        cur3 = nxt3;
    }
#pragma unroll
    for (int j = 0; j < 8; ++j) {
        int n = nid[te * 8 + j];
        if (n >= 0) {
            half4 o;
            o[0] = (_Float16)acc[j][0];
            o[1] = (_Float16)acc[j][1];
            o[2] = (_Float16)acc[j][2];
            o[3] = (_Float16)acc[j][3];
            *(half4*)(O + (size_t)n * DIM + tc * 4) = o;
        }
    }
}

// v: 128-node type-uniform chunk MFMA GEMM (value path: f16-tolerant)
__global__ __launch_bounds__(256) void vproj_kernel(
    const _Float16* __restrict__ hF, const int* __restrict__ ntype,
    const _Float16* __restrict__ WvT, const int* __restrict__ nlist,
    _Float16* __restrict__ vout) {
    __shared__ int nid[128];
    int tid = threadIdx.x;
    if (tid < 128) nid[tid] = nlist[blockIdx.x * 128 + tid];
    __syncthreads();
    if (nid[0] < 0) return;
    int t = ntype[nid[0]];
    int wv = tid >> 6, lane = tid & 63, l16 = lane & 15, quad = lane >> 4;
    int r0 = wv * 32;
    int nA[2];
#pragma unroll
    for (int m = 0; m < 2; ++m) nA[m] = nid[r0 + m * 16 + l16];
    const _Float16* B = WvT + (t << 14);
    f32x4 acc[2][8];
#pragma unroll
    for (int m = 0; m < 2; ++m)
#pragma unroll
        for (int c = 0; c < 8; ++c) acc[m][c] = (f32x4){0.f, 0.f, 0.f, 0.f};
    for (int kk = 0; kk < 4; ++kk) {
        int kb = kk * 32 + quad * 8;
        half8 a[2];
#pragma unroll
        for (int m = 0; m < 2; ++m)
            a[m] = (nA[m] >= 0)
                       ? *(const half8*)(hF + (size_t)nA[m] * DIM + kb)
                       : (half8){0, 0, 0, 0, 0, 0, 0, 0};
#pragma unroll
        for (int c = 0; c < 8; ++c) {
            half8 b = *(const half8*)(B + (c * 16 + l16) * DIM + kb);
#pragma unroll
            for (int m = 0; m < 2; ++m)
                acc[m][c] = __builtin_amdgcn_mfma_f32_16x16x32_f16(
                    a[m], b, acc[m][c], 0, 0, 0);
        }
    }
#pragma unroll
    for (int m = 0; m < 2; ++m)
#pragma unroll
        for (int c = 0; c < 8; ++c)
#pragma unroll
            for (int rg = 0; rg < 4; ++rg) {
                int node = nid[r0 + m * 16 + quad * 4 + rg];
                if (node >= 0)
                    vout[(size_t)node * DIM + c * 16 + l16] =
                        (_Float16)acc[m][c][rg];
            }
}

// ---------------------------------------------------------------------------
// nr_gemm v6 (R16-proven): one block = one rel; B register-resident; stream
// NR3_ITERS x 64-row tiles with double-buffered A prefetch.
// Pass 1: Out=KA, A=kF, B=attT, scale=pri*rsqrt. Pass 2: Out=VMF, A=vF,
// B=msgT, scale=1.
// ---------------------------------------------------------------------------
__global__ __launch_bounds__(256, 2) void nr_gemm3_kernel(
    const _Float16* __restrict__ A, const _Float16* __restrict__ B8,
    _Float16* __restrict__ Out, const float* __restrict__ pri, int isU) {
    __shared__ _Float16 stage[4][16][136];
    int bid = blockIdx.x;
    int rel = bid / NR3_CHUNKS;
    int chunk = bid - rel * NR3_CHUNKS;
    float scale = isU ? pri[rel] * RSQRT_DK : 1.0f;
    const _Float16* Bb = B8 + (rel << 14);
    int tid = threadIdx.x;
    int wv = tid >> 6, lane = tid & 63;
    int l16 = lane & 15, quad = lane >> 4;

    // B fragments once: bfrag[c][kk] covers B-row c*16+l16, k=kk*32+quad*8
    half8 bfrag[8][4];
#pragma unroll
    for (int c = 0; c < 8; ++c)
#pragma unroll
        for (int kk = 0; kk < 4; ++kk)
            bfrag[c][kk] =
                *(const half8*)(Bb + (c * 16 + l16) * DIM + kk * 32 + quad * 8);

    _Float16* Orel = Out + (size_t)rel * N_NODES * DIM;
    int base = chunk * NR3_ROWS + wv * 16;  // this wave's first tile row

    // prefetch tile 0
    half8 aNow[4], aNext[4];
    {
        int nodeA = base + l16;
#pragma unroll
        for (int kk = 0; kk < 4; ++kk)
            aNow[kk] = (nodeA < N_NODES)
                           ? *(const half8*)(A + (size_t)nodeA * DIM +
                                             kk * 32 + quad * 8)
                           : (half8){0, 0, 0, 0, 0, 0, 0, 0};
    }

    for (int it = 0; it < NR3_ITERS; ++it) {
        int row0 = base + it * 64;
        // prefetch next tile's A while this tile computes
        if (it + 1 < NR3_ITERS) {
            int nodeA = row0 + 64 + l16;
#pragma unroll
            for (int kk = 0; kk < 4; ++kk)
                aNext[kk] = (nodeA < N_NODES)
                                ? *(const half8*)(A + (size_t)nodeA * DIM +
                                                  kk * 32 + quad * 8)
                                : (half8){0, 0, 0, 0, 0, 0, 0, 0};
        }
        f32x4 acc[8];
#pragma unroll
        for (int c = 0; c < 8; ++c) acc[c] = (f32x4){0.f, 0.f, 0.f, 0.f};
#pragma unroll
        for (int kk = 0; kk < 4; ++kk)
#pragma unroll
            for (int c = 0; c < 8; ++c)
                acc[c] = __builtin_amdgcn_mfma_f32_16x16x32_f16(
                    bfrag[c][kk], aNow[kk], acc[c], 0, 0, 0);
        // stage transposed acc into wave-private LDS: row = local node l16,
        // feature = c*16 + quad*4 + rg
#pragma unroll
        for (int c = 0; c < 8; ++c) {
            half4 o;
#pragma unroll
            for (int rg = 0; rg < 4; ++rg)
                o[rg] = (_Float16)(acc[c][rg] * scale);
            *(half4*)&stage[wv][l16][c * 16 + quad * 4] = o;
        }
        // read back row-wise: 4 x (4 rows x 256B) = 1KiB contiguous stores
        _Float16* Op = Orel + (size_t)row0 * DIM;
#pragma unroll
        for (int s = 0; s < 4; ++s) {
            int row = s * 4 + quad;
            if (row0 + row < N_NODES) {
                half8 v = *(const half8*)&stage[wv][row][l16 * 8];
                *(half8*)(Op + (size_t)row * DIM + l16 * 8) = v;
            }
        }
#pragma unroll
        for (int kk = 0; kk < 4; ++kk) aNow[kk] = aNext[kk];
    }
}

// ---------------------------------------------------------------------------
// attend v4 (R22): score = kA[rel][src] . q[dst]. One gather per edge in
// phase 1 (kA replaces k-gather + U-read); q[dst] register-resident; online
// per-rel softmax (R21); no LDS at all.
// ---------------------------------------------------------------------------
__global__ __launch_bounds__(256) void attend_kernel(
    const _Float16* __restrict__ KA, const _Float16* __restrict__ qF,
    const _Float16* __restrict__ VMF, const int* __restrict__ dpr,
    const int* __restrict__ doff, const int* __restrict__ dcnt,
    _Float16* __restrict__ aggF) {
    int wv = threadIdx.x >> 6, lane = threadIdx.x & 63;
    int dst = blockIdx.x * 4 + wv;
    if (dst >= N_NODES) return;
    int l16 = lane & 15, g = lane >> 4, l8 = lane & 7;
    int beg = doff[dst], cnt = dcnt[dst];

    // q[dst] fragment: 8 halves per lane, register-resident for the kernel
    half8 qv = *(const half8*)(qF + (size_t)dst * DIM + l16 * 8);

    float m_own = -3e38f, sum_own = 0.f;
    float s0 = 0.f, s1 = 0.f, s2 = 0.f;
    int p0 = 0, p1 = 0, p2 = 0;

    // phase 1: scores; park (s, pr); ONLINE per-rel (max, sum) on owning lane
    for (int j0 = 0; j0 < cnt; j0 += 4) {
        int j = j0 + g;
        bool valid = j < cnt;
        int pr = valid ? dpr[beg + j] : 0;
        int src = pr >> 3, rel = pr & 7;
        half8 kv = *(const half8*)(KA + ((size_t)rel * N_NODES + src) * DIM +
                                   l16 * 8);
        float sa = 0.f, sb = 0.f;
#pragma unroll
        for (int i = 0; i < 4; ++i) sa += (float)kv[i] * (float)qv[i];
#pragma unroll
        for (int i = 4; i < 8; ++i) sb += (float)kv[i] * (float)qv[i];
        float s = sa + sb;
        s += __shfl_xor(s, 1, 16);
        s += __shfl_xor(s, 2, 16);
        s += __shfl_xor(s, 4, 16);
        s += __shfl_xor(s, 8, 16);
        if (!valid) s = -3e38f;
        int slot = j0 >> 6;            // wave-uniform
        int idx = (j0 >> 2) & 15;      // wave-uniform
        if (l16 == idx) {
            if (slot == 0) { s0 = s; p0 = pr; }
            else if (slot == 1) { s1 = s; p1 = pr; }
            else if (slot == 2) { s2 = s; p2 = pr; }
        }
        if (valid && l8 == rel) {
            if (s > m_own) {
                sum_own *= __expf(m_own - s);  // 0 * exp(-huge) = 0 first time
                m_own = s;
            }
            sum_own += __expf(s - m_own);
        }
    }
    // joint merge of (m, sum) across the 4 groups (exp-rescale combine)
    {
        float m2 = __shfl_xor(m_own, 16, 64);
        float t2 = __shfl_xor(sum_own, 16, 64);
        float mn = fmaxf(m_own, m2);
        sum_own = sum_own * __expf(m_own - mn) + t2 * __expf(m2 - mn);
        m_own = mn;
        m2 = __shfl_xor(m_own, 32, 64);
        t2 = __shfl_xor(sum_own, 32, 64);
        mn = fmaxf(m_own, m2);
        sum_own = sum_own * __expf(m_own - mn) + t2 * __expf(m2 - mn);
        m_own = mn;
    }
    float inv_own = (sum_own > 0.f) ? 1.f / sum_own : 0.f;

    // phase 2: alpha = exp(s - m[rel]) * inv[rel]; acc += alpha * VM[rel][src]
    float acc[8] = {0.f, 0.f, 0.f, 0.f, 0.f, 0.f, 0.f, 0.f};
    for (int j0 = 0; j0 < cnt; j0 += 4) {
        int j = j0 + g;
        bool valid = j < cnt;
        int slot = j0 >> 6;
        int idx = (j0 >> 2) & 15;
        float s;
        int pr;
        if (slot < 3) {
            float sv = (slot == 0) ? s0 : (slot == 1) ? s1 : s2;
            int pv = (slot == 0) ? p0 : (slot == 1) ? p1 : p2;
            s = __shfl(sv, idx, 16);
            pr = __shfl(pv, idx, 16);
        } else {  // overflow fallback: recompute (cnt>192 ~ never at deg~10)
            pr = valid ? dpr[beg + j] : 0;
            int src = pr >> 3, rel = pr & 7;
            half8 kv = *(const half8*)(KA +
                                       ((size_t)rel * N_NODES + src) * DIM +
                                       l16 * 8);
            float sa = 0.f, sb = 0.f;
#pragma unroll
            for (int i = 0; i < 4; ++i) sa += (float)kv[i] * (float)qv[i];
#pragma unroll
            for (int i = 4; i < 8; ++i) sb += (float)kv[i] * (float)qv[i];
            s = sa + sb;
            s += __shfl_xor(s, 1, 16);
            s += __shfl_xor(s, 2, 16);
            s += __shfl_xor(s, 4, 16);
            s += __shfl_xor(s, 8, 16);
        }
        int rel = pr & 7, src = pr >> 3;
        float mr = __shfl(m_own, rel, 8);
        float iv = __shfl(inv_own, rel, 8);
        float alpha = valid ? __expf(s - mr) * iv : 0.f;
        half8 v = *(const half8*)(VMF + ((size_t)rel * N_NODES + src) * DIM +
                                  l16 * 8);
#pragma unroll
        for (int i = 0; i < 8; ++i) acc[i] += alpha * (float)v[i];
    }
    // merge acc across the 4 groups (each covers the full 128 dims)
#pragma unroll
    for (int i = 0; i < 8; ++i) {
        acc[i] += __shfl_xor(acc[i], 16, 64);
        acc[i] += __shfl_xor(acc[i], 32, 64);
    }
    if (g == 0) {
        half8 o;
#pragma unroll
        for (int i = 0; i < 8; ++i) o[i] = (_Float16)acc[i];
        *(half8*)(aggF + (size_t)dst * DIM + l16 * 8) = o;
    }
}

// out: 128-node type-uniform chunk MFMA GEMM, fp32 stores with sigmoid gate
__global__ __launch_bounds__(256) void out_kernel(
    const _Float16* __restrict__ aggF, const int* __restrict__ ntype,
    const _Float16* __restrict__ WaT, const float* __restrict__ skip,
    const int* __restrict__ nlist, float* __restrict__ out) {
    __shared__ int nid[128];
    int tid = threadIdx.x;
    if (tid < 128) nid[tid] = nlist[blockIdx.x * 128 + tid];
    __syncthreads();
    if (nid[0] < 0) return;
    int t = ntype[nid[0]];
    float sig = 1.f / (1.f + __expf(-skip[t]));
    int wv = tid >> 6, lane = tid & 63, l16 = lane & 15, quad = lane >> 4;
    int r0 = wv * 32;
    int nA[2];
#pragma unroll
    for (int m = 0; m < 2; ++m) nA[m] = nid[r0 + m * 16 + l16];
    const _Float16* B = WaT + (t << 14);
    f32x4 acc[2][8];
#pragma unroll
    for (int m = 0; m < 2; ++m)
#pragma unroll
        for (int c = 0; c < 8; ++c) acc[m][c] = (f32x4){0.f, 0.f, 0.f, 0.f};
    for (int kk = 0; kk < 4; ++kk) {
        int kb = kk * 32 + quad * 8;
        half8 a[2];
#pragma unroll
        for (int m = 0; m < 2; ++m)
            a[m] = (nA[m] >= 0)
                       ? *(const half8*)(aggF + (size_t)nA[m] * DIM + kb)
                       : (half8){0, 0, 0, 0, 0, 0, 0, 0};
#pragma unroll
        for (int c = 0; c < 8; ++c) {
            half8 b = *(const half8*)(B + (c * 16 + l16) * DIM + kb);
#pragma unroll
            for (int m = 0; m < 2; ++m)
                acc[m][c] = __builtin_amdgcn_mfma_f32_16x16x32_f16(
                    a[m], b, acc[m][c], 0, 0, 0);
        }
    }
#pragma unroll
    for (int m = 0; m < 2; ++m)
#pragma unroll
        for (int c = 0; c < 8; ++c)
#pragma unroll
            for (int rg = 0; rg < 4; ++rg) {
                int node = nid[r0 + m * 16 + quad * 4 + rg];
                if (node >= 0)
                    out[(size_t)node * DIM + c * 16 + l16] =
                        acc[m][c][rg] * sig;
            }
}

extern "C" void kernel_launch(void* const* d_in, const int* in_sizes, int n_in,
                              void* d_out, int out_size, void* d_ws,
                              size_t ws_size, hipStream_t stream) {
    const float* h = (const float*)d_in[0];
    const int* adj = (const int*)d_in[1];
    const int* etype = (const int*)d_in[2];
    const int* ntype = (const int*)d_in[3];
    const float* Wk = (const float*)d_in[6];
    const float* Wq = (const float*)d_in[7];
    const float* Wv = (const float*)d_in[8];
    const float* Wa = (const float*)d_in[9];
    const float* pri = (const float*)d_in[10];
    const float* att = (const float*)d_in[11];
    const float* msg = (const float*)d_in[12];
    const float* skip = (const float*)d_in[13];
    float* out = (float*)d_out;

    int* wsi = (int*)d_ws + OFF_INT;
    _Float16* wsh = (_Float16*)d_ws;
    _Float16* KA = wsh + (size_t)OFF_KA * 2;
    _Float16* hF = wsh + (size_t)OFF_HF * 2;
    _Float16* VMF = wsh + (size_t)OFF_VM * 2;
    _Float16* kF = wsh + (size_t)OFF_KF * 2;
    _Float16* qF = wsh + (size_t)OFF_QF * 2;
    _Float16* aggF = wsh + (size_t)OFF_AGGF * 2;
    _Float16* vF = wsh + (size_t)OFF_VF * 2;
    _Float16* attT = wsh + (size_t)OFF_ATTT * 2;
    _Float16* msgT = wsh + (size_t)OFF_MSGT * 2;
    _Float16* WvT = wsh + (size_t)OFF_WVT * 2;
    _Float16* WaT = wsh + (size_t)OFF_WAT * 2;

    init_kernel<<<(100000 + 255) / 256, 256, 0, stream>>>(wsi);
    convert_kernel<<<(RR * DIM * DIM + 255) / 256, 256, 0, stream>>>(
        att, msg, Wv, Wa, attT, msgT, WvT, WaT);
    hconv_kernel<<<(N_NODES * DIM / 4 + 255) / 256, 256, 0, stream>>>(h, hF);
    hist_kernel<<<GRID_E, 256, 0, stream>>>(ntype, adj, wsi);
    offsets_kernel<<<1, 1, 0, stream>>>(wsi);
    scanA_kernel<<<SCAN_BLOCKS, 256, 0, stream>>>(wsi);
    scanB_kernel<<<1, 256, 0, stream>>>(wsi);
    scanC_kernel<<<SCAN_BLOCKS, 256, 0, stream>>>(wsi);
    scatter_kernel<<<GRID_E, 256, 0, stream>>>(ntype, etype, adj, wsi);
    {
        dim3 g(CHUNK_GRID * 2, 2);  // x: 64-node chunks, y: w (k=0, q=1)
        kq_f32_kernel<<<g, 256, 0, stream>>>(h, ntype, Wk, Wq,
                                             wsi + IO_NLIST, kF, qF);
    }
    vproj_kernel<<<CHUNK_GRID, 256, 0, stream>>>(hF, ntype, WvT,
                                                 wsi + IO_NLIST, vF);
    // pass 1: KA = pri*rsqrt * (kF @ attT^T); writes over hF region (dead).
    // pass 2: VMF = vF @ msgT^T; writes over kF region (dead after pass 1).
    nr_gemm3_kernel<<<RR * NR3_CHUNKS, 256, 0, stream>>>(kF, attT, KA, pri, 1);
    nr_gemm3_kernel<<<RR * NR3_CHUNKS, 256, 0, stream>>>(vF, msgT, VMF, pri, 0);
    attend_kernel<<<(N_NODES + 3) / 4, 256, 0, stream>>>(
        KA, qF, VMF, wsi + IO_DPR, wsi + IO_DOFF, wsi + IO_DCNT, aggF);
    out_kernel<<<CHUNK_GRID, 256, 0, stream>>>(aggF, ntype, WaT, skip,
                                               wsi + IO_NLIST, out);
}